// Round 1
// 335.712 us; speedup vs baseline: 1.2498x; 1.2498x over previous
//
#include <hip/hip_runtime.h>

#define N_NODES 50000
#define E_EDGES 800000
#define IN_DIM 256
#define H_HEADS 4
#define F_OUT 64
#define EF_DIM 64
#define NT_TYPES 8
#define SLOPE 0.2f
#define HF 256  /* H*F */

typedef __attribute__((ext_vector_type(8))) short short8;
typedef __attribute__((ext_vector_type(4))) float f32x4;
typedef unsigned short ushort_t;
typedef unsigned long long u64;

// workspace layout (float element offsets)
#define FEATBF_OFF 0          /* N*HF bf16 = 6.4M floats */
#define EL_OFF   6400000
#define ER_OFF   6600000
#define EE_OFF   6800000
#define BT_OFF   6800064      /* 256x256 bf16 = 32768 floats */
#define INT_OFF  6832832
// int offsets within int region
#define DEG_IOFF     0        /* 50,000 */
#define CURSOR_IOFF  50000    /* 50,000 (adjacent: zeroed together) */
#define RL_IOFF      100000   /* 50,000: per-node exclusive prefix within 256-chunk */
#define PK_IOFF      150008   /* packed edges: 800,000 u64 (8B aligned) */
#define BO_IOFF      1750008  /* 256: chunk-sum exclusive prefix (196 used) */

#define NBLK_GEMM 782         /* ceil(50000/64) */
#define NBLK_HIST 3125        /* 800000/256 */
#define NCHUNK    196         /* ceil(50000/256) */

__device__ __forceinline__ ushort_t f2bf(float f) {
    unsigned u = __float_as_uint(f);
    u += 0x7fffu + ((u >> 16) & 1u);   // round-nearest-even
    return (ushort_t)(u >> 16);
}
__device__ __forceinline__ float bf2f(ushort_t b) {
    return __uint_as_float(((unsigned)b) << 16);
}

// ======================= K1: ee + cast_w + zero(deg,cursor) =======================
__global__ __launch_bounds__(256) void k1_prep(
    const float* __restrict__ edge_emb, const float* __restrict__ fc_e_w,
    const float* __restrict__ attn_e, const float* __restrict__ fc_w,
    float* __restrict__ ee, ushort_t* __restrict__ Bt, int* __restrict__ zero_region)
{
    const int b = blockIdx.x;
    if (b == 0) {
        const int c = threadIdx.x;
        const float ae = attn_e[c];
        const int lane = c & 63, h = c >> 6;
        for (int ty = 0; ty < NT_TYPES; ty++) {
            float v = 0.f;
            #pragma unroll 8
            for (int k = 0; k < EF_DIM; k++)
                v = fmaf(edge_emb[ty * EF_DIM + k], fc_e_w[k * (H_HEADS * EF_DIM) + c], v);
            float contrib = v * ae;
            #pragma unroll
            for (int m = 32; m >= 1; m >>= 1) contrib += __shfl_xor(contrib, m);
            if (lane == 0) ee[ty * H_HEADS + h] = contrib;
        }
    } else if (b <= 256) {
        const int k = b - 1, c = threadIdx.x;
        Bt[(size_t)c * 256 + k] = f2bf(fc_w[(size_t)k * 256 + c]);
    } else {
        const int idx = (b - 257) * 256 + threadIdx.x;
        if (idx < 2 * N_NODES) zero_region[idx] = 0;   // deg + cursor adjacent
    }
}

// ======================= K2: degree histogram =======================
__global__ __launch_bounds__(256) void k2_hist(
    const int* __restrict__ dst, int* __restrict__ deg)
{
    const int t = blockIdx.x * 256 + threadIdx.x;
    if (t < E_EDGES) atomicAdd(deg + dst[t], 1);
}

// ======================= K3a: per-chunk local scan (196 blocks) =======================
__global__ __launch_bounds__(256) void scanA(
    const int* __restrict__ deg, int* __restrict__ rl, int* __restrict__ bo)
{
    __shared__ int sm[256];
    const int c = blockIdx.x, t = threadIdx.x;
    const int g = c * 256 + t;
    const int v = (g < N_NODES) ? deg[g] : 0;
    sm[t] = v;
    __syncthreads();
    int val = v;
    #pragma unroll
    for (int o = 1; o < 256; o <<= 1) {
        int x = (t >= o) ? sm[t - o] : 0;
        __syncthreads();
        val += x;
        sm[t] = val;
        __syncthreads();
    }
    if (g < N_NODES) rl[g] = val - v;   // exclusive within chunk
    if (t == 255) bo[c] = val;          // chunk total
}

// ======================= K3b: scan chunk sums in place (1 tiny block) =======================
__global__ __launch_bounds__(256) void scanB(int* __restrict__ bo)
{
    __shared__ int sm[256];
    const int t = threadIdx.x;
    const int v = (t < NCHUNK) ? bo[t] : 0;
    sm[t] = v;
    __syncthreads();
    int val = v;
    #pragma unroll
    for (int o = 1; o < 256; o <<= 1) {
        int x = (t >= o) ? sm[t - o] : 0;
        __syncthreads();
        val += x;
        sm[t] = val;
        __syncthreads();
    }
    if (t < NCHUNK) bo[t] = val - v;    // exclusive chunk offsets
}

// ======================= K4: MFMA GEMM || scatter =======================
__device__ __forceinline__ void gemm_body(
    const float* __restrict__ nfeat, const ushort_t* __restrict__ Bt,
    const float* __restrict__ attn_l, const float* __restrict__ attn_r,
    ushort_t* __restrict__ feat, float* __restrict__ el, float* __restrict__ er,
    int blk)
{
    const int w    = threadIdx.x >> 6;
    const int lane = threadIdx.x & 63;
    const int n16  = lane & 15;
    const int quad = lane >> 4;
    const int row0 = blk * 64;

    f32x4 acc[4][4];
    #pragma unroll
    for (int rt = 0; rt < 4; rt++)
        #pragma unroll
        for (int ct = 0; ct < 4; ct++)
            acc[rt][ct] = (f32x4){0.f, 0.f, 0.f, 0.f};

    for (int kb = 0; kb < IN_DIM; kb += 32) {
        short8 a[4], b[4];
        #pragma unroll
        for (int rt = 0; rt < 4; rt++) {
            int r = row0 + rt * 16 + n16;
            r = r < N_NODES ? r : N_NODES - 1;
            const float* p = nfeat + (size_t)r * IN_DIM + kb + quad * 8;
            const float4 v0 = *(const float4*)p;
            const float4 v1 = *(const float4*)(p + 4);
            short8 t;
            t[0] = (short)f2bf(v0.x); t[1] = (short)f2bf(v0.y);
            t[2] = (short)f2bf(v0.z); t[3] = (short)f2bf(v0.w);
            t[4] = (short)f2bf(v1.x); t[5] = (short)f2bf(v1.y);
            t[6] = (short)f2bf(v1.z); t[7] = (short)f2bf(v1.w);
            a[rt] = t;
        }
        #pragma unroll
        for (int ct = 0; ct < 4; ct++) {
            const int c = w * 64 + ct * 16 + n16;
            b[ct] = *(const short8*)(Bt + (size_t)c * 256 + kb + quad * 8);
        }
        #pragma unroll
        for (int rt = 0; rt < 4; rt++)
            #pragma unroll
            for (int ct = 0; ct < 4; ct++)
                acc[rt][ct] = __builtin_amdgcn_mfma_f32_16x16x32_bf16(a[rt], b[ct], acc[rt][ct], 0, 0, 0);
    }

    float alv[4], arv[4];
    #pragma unroll
    for (int ct = 0; ct < 4; ct++) {
        alv[ct] = attn_l[w * 64 + ct * 16 + n16];
        arv[ct] = attn_r[w * 64 + ct * 16 + n16];
    }
    #pragma unroll
    for (int rt = 0; rt < 4; rt++) {
        #pragma unroll
        for (int reg = 0; reg < 4; reg++) {
            const int row = row0 + rt * 16 + quad * 4 + reg;
            const bool ok = row < N_NODES;
            float pl = 0.f, pr = 0.f;
            #pragma unroll
            for (int ct = 0; ct < 4; ct++) {
                const float v = acc[rt][ct][reg];
                if (ok) feat[(size_t)row * HF + w * 64 + ct * 16 + n16] = f2bf(v);
                pl = fmaf(v, alv[ct], pl);
                pr = fmaf(v, arv[ct], pr);
            }
            #pragma unroll
            for (int m = 8; m >= 1; m >>= 1) {
                pl += __shfl_xor(pl, m);
                pr += __shfl_xor(pr, m);
            }
            if (n16 == 0 && ok) {
                el[row * H_HEADS + w] = pl;
                er[row * H_HEADS + w] = pr;
            }
        }
    }
}

__global__ __launch_bounds__(256) void k4_gemm_scatter(
    const float* __restrict__ nfeat, const ushort_t* __restrict__ Bt,
    const float* __restrict__ attn_l, const float* __restrict__ attn_r,
    ushort_t* __restrict__ feat, float* __restrict__ el, float* __restrict__ er,
    const int* __restrict__ src, const int* __restrict__ dst, const int* __restrict__ etype,
    const int* __restrict__ rl, const int* __restrict__ bo,
    int* __restrict__ cursor, u64* __restrict__ pk)
{
    if (blockIdx.x < NBLK_GEMM) {
        gemm_body(nfeat, Bt, attn_l, attn_r, feat, el, er, blockIdx.x);
    } else {
        const int t = (blockIdx.x - NBLK_GEMM) * 256 + threadIdx.x;
        if (t < E_EDGES) {
            const int d = dst[t];
            const int pos = bo[d >> 8] + rl[d] + atomicAdd(cursor + d, 1);
            pk[pos] = (u64)src[t] | ((u64)etype[t] << 16) | ((u64)t << 32);
        }
    }
}

// ======================= K5: fused softmax + aggregation (v5: uint2 gather) =======================
__global__ __launch_bounds__(256) void agg_kernel(
    const u64* __restrict__ pk, const int* __restrict__ rl, const int* __restrict__ bo,
    const int* __restrict__ degarr,
    const float* __restrict__ el, const float* __restrict__ er,
    const float* __restrict__ ee, const ushort_t* __restrict__ feat,
    float* __restrict__ a_out, float* __restrict__ rst)
{
    const int d = blockIdx.x;
    const int t = threadIdx.x;
    const int h = t >> 6, lane = t & 63;
    const int off = bo[d >> 8] + rl[d];
    const int deg = degarr[d];

    __shared__ int sS[256];
    __shared__ int sE[256];
    __shared__ float sc[4][256];

    if (deg <= 248) {                      // degP <= 256 guaranteed
        const int degP = (deg + 15) & ~15; // pad to multiple of 16 with zero-weight edges
        if (t < deg) {
            const u64 p = pk[off + t];
            const int s  = (int)(p & 0xffffu);
            const int ty = (int)((p >> 16) & 0xffu);
            sS[t] = s;
            sE[t] = (int)(p >> 32);
            const float4 el4 = *(const float4*)(el + s * 4);
            const float4 er4 = *(const float4*)(er + d * 4);
            const float4 ee4 = *(const float4*)(ee + ty * 4);
            float v;
            v = el4.x + er4.x + ee4.x; sc[0][t] = v > 0.f ? v : SLOPE * v;
            v = el4.y + er4.y + ee4.y; sc[1][t] = v > 0.f ? v : SLOPE * v;
            v = el4.z + er4.z + ee4.z; sc[2][t] = v > 0.f ? v : SLOPE * v;
            v = el4.w + er4.w + ee4.w; sc[3][t] = v > 0.f ? v : SLOPE * v;
        } else if (t < degP) {
            sS[t] = 0;                     // zero-weight pad -> row 0 (L2-hot), contributes 0
            sc[0][t] = 0.f; sc[1][t] = 0.f; sc[2][t] = 0.f; sc[3][t] = 0.f;
        }
        __syncthreads();

        float m = -INFINITY;
        for (int i = lane; i < deg; i += 64) m = fmaxf(m, sc[h][i]);
        #pragma unroll
        for (int w = 32; w >= 1; w >>= 1) m = fmaxf(m, __shfl_xor(m, w));

        // exp pass: cache exp in LDS (avoids recomputing __expf in normalize)
        float s = 0.f;
        for (int i = lane; i < deg; i += 64) {
            const float e = __expf(sc[h][i] - m);
            sc[h][i] = e;
            s += e;
        }
        #pragma unroll
        for (int w = 32; w >= 1; w >>= 1) s += __shfl_xor(s, w);
        const float inv = 1.f / s;

        // normalize in LDS (component h touched only by wave h); pads stay 0
        for (int i = lane; i < deg; i += 64) {
            const float a = sc[h][i] * inv;
            sc[h][i] = a;
            a_out[sE[i] * 4 + h] = a;
        }
        __syncthreads();   // (wave h only reads sc[h][*] below; barrier keeps pads/normalized visible)

        // aggregation: quarter-wave per edge, uint2 loads (4 bf16 / load),
        // 4 independent 512B wave-loads in flight per iteration
        const int q   = lane >> 4;         // edge slot mod 4
        const int l16 = lane & 15;         // covers f = l16*4 .. l16*4+3
        const uint2* fb = (const uint2*)feat;   // row s: 64 uint2; head h at +h*16
        float a0 = 0.f, a1 = 0.f, a2 = 0.f, a3 = 0.f;
        for (int i = 0; i < degP; i += 16) {
            int sn[4]; float aw[4];
            #pragma unroll
            for (int j = 0; j < 4; j++) {
                const int idx = i + j * 4 + q;
                sn[j] = sS[idx];
                aw[j] = sc[h][idx];
            }
            uint2 u[4];
            #pragma unroll
            for (int j = 0; j < 4; j++)
                u[j] = fb[(size_t)sn[j] * 64 + h * 16 + l16];
            #pragma unroll
            for (int j = 0; j < 4; j++) {
                a0 = fmaf(aw[j], __uint_as_float(u[j].x << 16),          a0);
                a1 = fmaf(aw[j], __uint_as_float(u[j].x & 0xffff0000u),  a1);
                a2 = fmaf(aw[j], __uint_as_float(u[j].y << 16),          a2);
                a3 = fmaf(aw[j], __uint_as_float(u[j].y & 0xffff0000u),  a3);
            }
        }
        a0 += __shfl_xor(a0, 16); a0 += __shfl_xor(a0, 32);
        a1 += __shfl_xor(a1, 16); a1 += __shfl_xor(a1, 32);
        a2 += __shfl_xor(a2, 16); a2 += __shfl_xor(a2, 32);
        a3 += __shfl_xor(a3, 16); a3 += __shfl_xor(a3, 32);
        if (q == 0) {
            float4 o = {a0, a1, a2, a3};
            *(float4*)(rst + (size_t)d * HF + h * 64 + l16 * 4) = o;
        }
    } else {
        // fallback for large deg
        const float erh = er[d * 4 + h];
        float m = -INFINITY;
        for (int i = lane; i < deg; i += 64) {
            const u64 p = pk[off + i];
            float v = el[(int)(p & 0xffffu) * 4 + h] + erh + ee[(int)((p >> 16) & 0xffu) * 4 + h];
            v = v > 0.f ? v : SLOPE * v;
            m = fmaxf(m, v);
        }
        #pragma unroll
        for (int w = 32; w >= 1; w >>= 1) m = fmaxf(m, __shfl_xor(m, w));
        float s = 0.f;
        for (int i = lane; i < deg; i += 64) {
            const u64 p = pk[off + i];
            float v = el[(int)(p & 0xffffu) * 4 + h] + erh + ee[(int)((p >> 16) & 0xffu) * 4 + h];
            v = v > 0.f ? v : SLOPE * v;
            s += __expf(v - m);
        }
        #pragma unroll
        for (int w = 32; w >= 1; w >>= 1) s += __shfl_xor(s, w);
        const float inv = 1.f / s;
        float acc = 0.f;
        for (int i = 0; i < deg; i++) {
            const u64 p = pk[off + i];
            const int sn = (int)(p & 0xffffu);
            float v = el[sn * 4 + h] + erh + ee[(int)((p >> 16) & 0xffu) * 4 + h];
            v = v > 0.f ? v : SLOPE * v;
            const float a = __expf(v - m) * inv;
            if (lane == 0) a_out[(int)(p >> 32) * 4 + h] = a;
            acc = fmaf(a, bf2f(feat[(size_t)sn * HF + h * 64 + lane]), acc);
        }
        rst[(size_t)d * HF + h * 64 + lane] = acc;
    }
}

extern "C" void kernel_launch(void* const* d_in, const int* in_sizes, int n_in,
                              void* d_out, int out_size, void* d_ws, size_t ws_size,
                              hipStream_t stream) {
    const float* nfeat    = (const float*)d_in[0];
    const float* fc_w     = (const float*)d_in[1];
    const float* fc_e_w   = (const float*)d_in[2];
    const float* attn_l   = (const float*)d_in[3];
    const float* attn_r   = (const float*)d_in[4];
    const float* attn_e   = (const float*)d_in[5];
    const float* edge_emb = (const float*)d_in[6];
    const int*   src      = (const int*)d_in[7];
    const int*   dst      = (const int*)d_in[8];
    const int*   etype    = (const int*)d_in[9];

    float* ws = (float*)d_ws;
    ushort_t* feat = (ushort_t*)(ws + FEATBF_OFF);
    float* el   = ws + EL_OFF;
    float* er   = ws + ER_OFF;
    float* ee   = ws + EE_OFF;
    ushort_t* Bt = (ushort_t*)(ws + BT_OFF);
    int*   ip      = (int*)(ws + INT_OFF);
    int*   deg     = ip + DEG_IOFF;
    int*   cursor  = ip + CURSOR_IOFF;
    int*   rl      = ip + RL_IOFF;
    u64*   pk      = (u64*)(ip + PK_IOFF);
    int*   bo      = ip + BO_IOFF;

    float* rst   = (float*)d_out;                              // [N,H,F]
    float* a_out = (float*)d_out + (size_t)N_NODES * HF;       // [E,H]

    // K1: ee (1 blk) + cast_w (256) + zero deg/cursor (391)
    k1_prep<<<648, 256, 0, stream>>>(edge_emb, fc_e_w, attn_e, fc_w, ee, Bt, deg);
    // K2: degree histogram (needs zeroed deg)
    k2_hist<<<NBLK_HIST, 256, 0, stream>>>(dst, deg);
    // K3: two-level parallel scan (replaces 1-block serial scan)
    scanA<<<NCHUNK, 256, 0, stream>>>(deg, rl, bo);
    scanB<<<1, 256, 0, stream>>>(bo);
    // K4: GEMM (needs Bt) || scatter (needs rl/bo/cursor) — overlap compute & atomics
    k4_gemm_scatter<<<NBLK_GEMM + NBLK_HIST, 256, 0, stream>>>(
        nfeat, Bt, attn_l, attn_r, feat, el, er,
        src, dst, etype, rl, bo, cursor, pk);
    // K5: fused softmax + aggregation
    agg_kernel<<<N_NODES, 256, 0, stream>>>(pk, rl, bo, deg, el, er, ee, feat, a_out, rst);
}